// Round 13
// baseline (160.412 us; speedup 1.0000x reference)
//
#include <hip/hip_runtime.h>
#include <hip/hip_cooperative_groups.h>

namespace cg = cooperative_groups;

#define BATCH 8
#define NPRED 25200
#define NCLS 80
#define ROWW 85
#define TOPKK 2048
#define MAXDET 300
#define CANDMAX 4096
#define NBUCKET 4096
#define CONF_T 0.2f
#define IOU_T 0.6f
#define CLS_OFF 4096.0f

#define MASKN 384              // candidates with precomputed masks
#define MCH (MASKN / 64)       // 6 chunks
#define MW 13                  // u32 stride per mask row (gcd(13,32)=1: conflict-free)
#define NTILE (BATCH * NPRED / 64)   // 3150
#define GRID 256
#define BLK 1024

typedef unsigned long long u64;
typedef unsigned int u32;

__device__ __forceinline__ int bucket_of_key(u64 k) {
    float sc = __uint_as_float((u32)(k >> 32));
    int bkt = (int)(sc * (float)NBUCKET);
    return (bkt > NBUCKET - 1) ? (NBUCKET - 1) : bkt;
}

struct FinishLDS {
    union {
        u32 bstartL[NBUCKET];            // 16 KB (rank phase)
        struct {
            u32 masks32[MASKN * MW];     // 19968 B
            float4 cbx[MASKN];           // 6 KB
            float carea[MASKN];          // 1.5 KB
            float4 kb[MAXDET];           // 4.7 KB
        } nms;
    } v;
    u64 candL[CANDMAX];                  // 32 KB
    unsigned short rank2cand[TOPKK];     // 4 KB
    float4 sbox[MASKN];                  // 6 KB
    float sscore[MASKN];                 // 1.5 KB
    float scls[MASKN];                   // 1.5 KB
    u64 validw[MCH];
};

__global__ __launch_bounds__(BLK) void k_mega(
    const float* __restrict__ preds,
    u64* __restrict__ keys,
    unsigned char* __restrict__ cls8,
    u32* __restrict__ bstart_g,
    u32* __restrict__ balloc_g,
    int* __restrict__ tb_g,
    u32* __restrict__ stored_g,
    u64* __restrict__ cand_g,
    float* __restrict__ out)
{
    __shared__ union {
        float4 rows4[1364];              // 21.8 KB  (score tile)
        u32 histL[NBUCKET];              // 16 KB    (scan)
        FinishLDS fin;                   // ~78.6 KB (finish)
    } L;
    __shared__ u32 wtot[16];
    __shared__ u32 wsuf[16];
    __shared__ int s_tb;
    __shared__ u32 s_stored;

    cg::grid_group grid = cg::this_grid();
    const int bid = blockIdx.x;
    const int t = threadIdx.x;
    const int lane = t & 63;
    const int wave = t >> 6;

    // ================= P1: score/key (grid-stride tiles) =================
    for (int tile = bid; tile < NTILE; tile += GRID) {
        const size_t rowbase = (size_t)tile * 64;
        const float4* src = reinterpret_cast<const float4*>(preds + rowbase * ROWW);
        for (int q = wave; q < 21; q += 16) {
            __builtin_amdgcn_global_load_lds(
                (const __attribute__((address_space(1))) void*)(src + q * 64 + lane),
                (__attribute__((address_space(3))) void*)(L.rows4 + q * 64),
                16, 0, 0);
        }
        if (t < 16) L.rows4[1344 + t] = src[1344 + t];
        __syncthreads();

        const float* rows = reinterpret_cast<const float*>(L.rows4);
        const int r = t >> 4;          // row (0..63), 16 lanes per row
        const int j = t & 15;
        const float* p = rows + r * ROWW;
        const float obj = p[4];

        // classes j, j+16, ..., j+64 (5 per lane); strict > keeps lowest index
        float best = -1.0f;
        int bi = 0;
        #pragma unroll
        for (int tt = 0; tt < 5; ++tt) {
            int c = j + 16 * tt;
            float s = __fmul_rn(obj, p[5 + c]);
            if (s > best) { best = s; bi = c; }
        }
        // 16-lane merge (stays within the row's lane group; xor d<16)
        #pragma unroll
        for (int d = 1; d <= 8; d <<= 1) {
            float os = __shfl_xor(best, d);
            int oi = __shfl_xor(bi, d);
            if (os > best || (os == best && oi < bi)) { best = os; bi = oi; }
        }

        if (j == 0) {
            unsigned gid = (unsigned)rowbase + r;
            u64 key = 0ull;
            if (best > CONF_T) {
                key = ((u64)__float_as_uint(best) << 32) | (0xFFFFFFFFu - (gid % NPRED));
            }
            keys[gid] = key;
            cls8[gid] = (unsigned char)bi;
        }
        __syncthreads();   // LDS reused next tile
    }

    grid.sync();

    // ================= P2: per-batch hist + suffix scan (blocks 0..7) =================
    if (bid < BATCH) {
        const int b = bid;
        for (int i = t; i < NBUCKET; i += BLK) L.histL[i] = 0u;
        __syncthreads();

        const uint4* k4 = reinterpret_cast<const uint4*>(keys + (size_t)b * NPRED);
        for (int i = t; i < NPRED / 2; i += BLK) {
            uint4 v = k4[i];
            u64 ka = ((u64)v.y << 32) | v.x;
            u64 kb = ((u64)v.w << 32) | v.z;
            if (ka) atomicAdd(&L.histL[bucket_of_key(ka)], 1u);
            if (kb) atomicAdd(&L.histL[bucket_of_key(kb)], 1u);
        }
        __syncthreads();

        u32 h0 = L.histL[4 * t], h1 = L.histL[4 * t + 1];
        u32 h2 = L.histL[4 * t + 2], h3 = L.histL[4 * t + 3];
        u32 ps = h0 + h1 + h2 + h3;

        u32 v = ps;
        #pragma unroll
        for (int off = 1; off < 64; off <<= 1) {
            u32 u2 = __shfl_down(v, off);
            if (lane + off < 64) v += u2;
        }
        if (lane == 0) wtot[wave] = v;
        __syncthreads();
        if (t < 16) {
            u32 w = wtot[t];
            u32 s = w;
            #pragma unroll
            for (int off = 1; off < 16; off <<= 1) {
                u32 u2 = __shfl_down(s, off);
                if (t + off < 16) s += u2;
            }
            wsuf[t] = s - w;
        }
        if (t == 0) s_tb = 0;
        __syncthreads();
        u32 suffix_t = v + wsuf[wave];
        u32 snext = suffix_t - ps;

        u32 b3 = snext;
        u32 b2 = b3 + h3;
        u32 b1 = b2 + h2;
        u32 b0 = b1 + h1;
        const size_t B0 = (size_t)b * NBUCKET;
        bstart_g[B0 + 4 * t + 0] = b0;
        bstart_g[B0 + 4 * t + 1] = b1;
        bstart_g[B0 + 4 * t + 2] = b2;
        bstart_g[B0 + 4 * t + 3] = b3;
        balloc_g[B0 + 4 * t + 0] = b0;
        balloc_g[B0 + 4 * t + 1] = b1;
        balloc_g[B0 + 4 * t + 2] = b2;
        balloc_g[B0 + 4 * t + 3] = b3;

        if (t == 0) s_stored = (suffix_t < (u32)CANDMAX) ? suffix_t : (u32)CANDMAX;
        __syncthreads();
        {
            u32 c3 = b3 + h3, c2 = b2 + h2, c1 = b1 + h1, c0 = b0 + h0;
            if (c3 >= TOPKK && b3 < TOPKK) { s_tb = 4 * t + 3; s_stored = (c3 < (u32)CANDMAX) ? c3 : (u32)CANDMAX; }
            if (c2 >= TOPKK && b2 < TOPKK) { s_tb = 4 * t + 2; s_stored = (c2 < (u32)CANDMAX) ? c2 : (u32)CANDMAX; }
            if (c1 >= TOPKK && b1 < TOPKK) { s_tb = 4 * t + 1; s_stored = (c1 < (u32)CANDMAX) ? c1 : (u32)CANDMAX; }
            if (c0 >= TOPKK && b0 < TOPKK) { s_tb = 4 * t + 0; s_stored = (c0 < (u32)CANDMAX) ? c0 : (u32)CANDMAX; }
        }
        __syncthreads();
        if (t == 0) { tb_g[b] = s_tb; stored_g[b] = s_stored; }
    }

    grid.sync();

    // ================= P3: compaction (grid-stride, vectorized) =================
    {
        unsigned i2 = bid * BLK + t;
        if (i2 < BATCH * NPRED / 2) {
            uint4 v = reinterpret_cast<const uint4*>(keys)[i2];
            int b = (int)(i2 / (NPRED / 2));
            int tb = tb_g[b];
            u64 ka = ((u64)v.y << 32) | v.x;
            u64 kb = ((u64)v.w << 32) | v.z;
            if (ka) {
                int bkt = bucket_of_key(ka);
                if (bkt >= tb) {
                    u32 slot = atomicAdd(&balloc_g[(size_t)b * NBUCKET + bkt], 1u);
                    if (slot < CANDMAX) cand_g[(size_t)b * CANDMAX + slot] = ka;
                }
            }
            if (kb) {
                int bkt = bucket_of_key(kb);
                if (bkt >= tb) {
                    u32 slot = atomicAdd(&balloc_g[(size_t)b * NBUCKET + bkt], 1u);
                    if (slot < CANDMAX) cand_g[(size_t)b * CANDMAX + slot] = kb;
                }
            }
        }
    }

    grid.sync();

    // ================= P4: rank + mask-matrix NMS (blocks 0..7) =================
    if (bid >= BATCH) return;
    {
        const int b = bid;
        float* ob = out + (size_t)b * MAXDET * 6;
        const u32 stored = stored_g[b];
        const int tb = tb_g[b];
        const int tb2 = (tb > 0) ? tb - 1 : 0;

        for (int i = tb2 + t; i < NBUCKET; i += BLK)
            L.fin.v.bstartL[i] = bstart_g[(size_t)b * NBUCKET + i];
        for (int i = t; i < TOPKK; i += BLK) L.fin.rank2cand[i] = 0xFFFFu;
        for (int i = t; i < CANDMAX; i += BLK)
            if ((u32)i < stored) L.fin.candL[i] = cand_g[(size_t)b * CANDMAX + i];
        if (t < MASKN) {
            L.fin.sbox[t] = make_float4(0.f, 0.f, 0.f, 0.f);
            L.fin.sscore[t] = 0.f;
            L.fin.scls[t] = 0.f;
        }
        __syncthreads();

        // exact rank + top-384 gather
        for (u32 i = t; i < stored; i += BLK) {
            u64 k = L.fin.candL[i];
            int bkt = bucket_of_key(k);
            u32 base = L.fin.v.bstartL[bkt];
            u32 end = (bkt == 0) ? stored : L.fin.v.bstartL[bkt - 1];
            if (end > stored) end = stored;
            u32 r = base;
            for (u32 jx = base; jx < end; ++jx) r += (L.fin.candL[jx] > k) ? 1u : 0u;
            if (r < TOPKK) L.fin.rank2cand[r] = (unsigned short)i;
            if (r < MASKN) {
                float sc = __uint_as_float((u32)(k >> 32));
                unsigned idx = 0xFFFFFFFFu - (u32)(k & 0xFFFFFFFFu);
                const float* p = preds + ((size_t)b * NPRED + idx) * ROWW;
                float cx = p[0], cy = p[1], w = p[2], h = p[3];
                float hw = __fmul_rn(w, 0.5f);
                float hh = __fmul_rn(h, 0.5f);
                L.fin.sbox[r] = make_float4(__fsub_rn(cx, hw), __fsub_rn(cy, hh),
                                            __fadd_rn(cx, hw), __fadd_rn(cy, hh));
                L.fin.sscore[r] = sc;
                L.fin.scls[r] = (float)cls8[(size_t)b * NPRED + idx];
            }
        }
        __syncthreads();   // bstartL dead; union switches to nms

        // phase 1: offset boxes, areas, valid bits
        if (t < MASKN) {
            float sc = L.fin.sscore[t];
            float cl = L.fin.scls[t];
            float4 bb = L.fin.sbox[t];
            float off = __fmul_rn(cl, CLS_OFF);
            float4 obx = make_float4(__fadd_rn(bb.x, off), __fadd_rn(bb.y, off),
                                     __fadd_rn(bb.z, off), __fadd_rn(bb.w, off));
            L.fin.v.nms.cbx[t] = obx;
            L.fin.v.nms.carea[t] = __fmul_rn(__fsub_rn(obx.z, obx.x), __fsub_rn(obx.w, obx.y));
            u64 vb = __ballot(sc > CONF_T);
            if (lane == 0) L.fin.validw[wave] = vb;
        }
        __syncthreads();

        // phase 2: upper-triangle masks, 42 units over 16 waves
        for (int tu = 0; tu < 3; ++tu) {
            int uidx = wave + 16 * tu;
            if (uidx >= 42) break;
            int q, s;
            if (uidx < 12)      { q = 0; s = uidx; }
            else if (uidx < 22) { q = 1; s = uidx - 12 + 2; }
            else if (uidx < 30) { q = 2; s = uidx - 22 + 4; }
            else if (uidx < 36) { q = 3; s = uidx - 30 + 6; }
            else if (uidx < 40) { q = 4; s = uidx - 36 + 8; }
            else                { q = 5; s = uidx - 40 + 10; }

            const int r = q * 64 + lane;
            const float4 me = L.fin.v.nms.cbx[r];
            const float aA = L.fin.v.nms.carea[r];
            const int j0 = s * 32;
            u32 acc = 0u;
            #pragma unroll 8
            for (int jj = 0; jj < 32; ++jj) {
                const int jx = j0 + jj;
                float4 cb = L.fin.v.nms.cbx[jx];
                float lx = fmaxf(me.x, cb.x), ly = fmaxf(me.y, cb.y);
                float rx = fminf(me.z, cb.z), ry = fminf(me.w, cb.w);
                float iw = fmaxf(__fsub_rn(rx, lx), 0.0f);
                float ih = fmaxf(__fsub_rn(ry, ly), 0.0f);
                float inter = __fmul_rn(iw, ih);
                float denom = __fadd_rn(__fsub_rn(__fadd_rn(aA, L.fin.v.nms.carea[jx]), inter), 1e-9f);
                bool sv = inter > __fmul_rn(IOU_T, denom);
                acc |= ((u32)sv) << jj;
            }
            if (s == 2 * q || s == 2 * q + 1) {     // diagonal slice: keep only j > r
                int shift = r - j0;
                u32 dm = (shift < 0) ? ~0u : ((shift >= 31) ? 0u : (~0u << (shift + 1)));
                acc &= dm;
            }
            L.fin.v.nms.masks32[r * MW + s] = acc;
        }
        __syncthreads();
        if (wave != 0) return;

        // phase 3: wave-0 greedy resolve (upper-triangle semantics)
        const u64 below = (lane == 0) ? 0ull : (~0ull >> (64 - lane));
        u64 S[MCH];
        #pragma unroll
        for (int w = 0; w < MCH; ++w) S[w] = 0ull;
        int nk = 0;
        bool done = false, allfull = true;

        #pragma unroll
        for (int c = 0; c < MCH; ++c) {
            if (done) break;
            u64 vw = L.fin.validw[c];
            u64 eligible = vw & ~S[c];
            const int rbase = (c * 64 + lane) * MW;
            u64 Mu = ((u64)L.fin.v.nms.masks32[rbase + 2 * c + 1] << 32) |
                     (u64)L.fin.v.nms.masks32[rbase + 2 * c];
            bool elig = (eligible >> lane) & 1ull;
            if (eligible) {
                int cap = MAXDET - nk;
                u64 edge = __ballot(elig && ((Mu & eligible) != 0ull));
                u64 keptm;
                if (edge == 0ull) {
                    int rank = __popcll(eligible & below);
                    keptm = __ballot(elig && (rank < cap));
                } else {
                    u64 km = 0ull, supm = 0ull;
                    int cnt = 0;
                    for (int m = 0; m < 64 && cnt < cap; ++m) {
                        if (!((eligible >> m) & 1ull)) continue;
                        if ((supm >> m) & 1ull) continue;
                        km |= 1ull << m;
                        ++cnt;
                        supm |= __shfl(Mu, m);
                    }
                    keptm = km;
                }
                if ((keptm >> lane) & 1ull) {
                    int pos = nk + __popcll(keptm & below);
                    int i = c * 64 + lane;
                    float4 bb = L.fin.sbox[i];
                    L.fin.v.nms.kb[pos] = L.fin.v.nms.cbx[i];
                    float* row = ob + pos * 6;
                    row[0] = bb.x; row[1] = bb.y; row[2] = bb.z; row[3] = bb.w;
                    row[4] = L.fin.sscore[i]; row[5] = L.fin.scls[i];
                }
                nk += __popcll(keptm);
                if (nk >= MAXDET) {
                    done = true;
                } else if (keptm) {
                    for (int w = c + 1; w < MCH; ++w) {
                        u64 v2 = ((keptm >> lane) & 1ull)
                            ? (((u64)L.fin.v.nms.masks32[rbase + 2 * w + 1] << 32) |
                               (u64)L.fin.v.nms.masks32[rbase + 2 * w])
                            : 0ull;
                        v2 |= __shfl_xor(v2, 1);  v2 |= __shfl_xor(v2, 2);
                        v2 |= __shfl_xor(v2, 4);  v2 |= __shfl_xor(v2, 8);
                        v2 |= __shfl_xor(v2, 16); v2 |= __shfl_xor(v2, 32);
                        S[w] |= v2;
                    }
                }
            }
            if (vw != ~0ull) { allfull = false; break; }
        }

        // phase 4: exact fallback beyond MASKN (rarely taken)
        if (!done && allfull && nk < MAXDET) {
            __threadfence_block();
            for (int c = MCH; c < TOPKK / 64; ++c) {
                int r = c * 64 + lane;
                unsigned short ci = L.fin.rank2cand[r];
                bool valid = (ci != 0xFFFFu);
                u64 validmask = __ballot(valid);
                if (validmask == 0ull) break;

                float sc = 0.f, cl = 0.f;
                float bx1 = 0.f, by1 = 0.f, bx2 = 0.f, by2 = 0.f;
                if (valid) {
                    u64 k = L.fin.candL[ci];
                    sc = __uint_as_float((u32)(k >> 32));
                    unsigned idx = 0xFFFFFFFFu - (u32)(k & 0xFFFFFFFFu);
                    const float* p = preds + ((size_t)b * NPRED + idx) * ROWW;
                    float cx = p[0], cy = p[1], w = p[2], h = p[3];
                    float hw = __fmul_rn(w, 0.5f);
                    float hh = __fmul_rn(h, 0.5f);
                    bx1 = __fsub_rn(cx, hw); by1 = __fsub_rn(cy, hh);
                    bx2 = __fadd_rn(cx, hw); by2 = __fadd_rn(cy, hh);
                    cl = (float)cls8[(size_t)b * NPRED + idx];
                }
                float off = __fmul_rn(cl, CLS_OFF);
                float x1 = __fadd_rn(bx1, off), y1 = __fadd_rn(by1, off);
                float x2 = __fadd_rn(bx2, off), y2 = __fadd_rn(by2, off);
                float areaA = __fmul_rn(__fsub_rn(x2, x1), __fsub_rn(y2, y1));

                bool sup = false;
                for (int jx = 0; jx < nk; ++jx) {
                    float4 k4 = L.fin.v.nms.kb[jx];
                    float lx = fmaxf(x1, k4.x), ly = fmaxf(y1, k4.y);
                    float rx = fminf(x2, k4.z), ry = fminf(y2, k4.w);
                    float iw = fmaxf(__fsub_rn(rx, lx), 0.0f);
                    float ih = fmaxf(__fsub_rn(ry, ly), 0.0f);
                    float inter = __fmul_rn(iw, ih);
                    float areaB = __fmul_rn(__fsub_rn(k4.z, k4.x), __fsub_rn(k4.w, k4.y));
                    float denom = __fadd_rn(__fsub_rn(__fadd_rn(areaA, areaB), inter), 1e-9f);
                    if (inter > __fmul_rn(IOU_T, denom)) sup = true;
                }
                u64 supprev = __ballot(sup);

                u32 sb_lo = 0u, sb_hi = 0u;
                for (int m = 0; m < 64; ++m) {
                    float mx1 = __shfl(x1, m), my1 = __shfl(y1, m);
                    float mx2 = __shfl(x2, m), my2 = __shfl(y2, m);
                    float lx = fmaxf(x1, mx1), ly = fmaxf(y1, my1);
                    float rx = fminf(x2, mx2), ry = fminf(y2, my2);
                    float iw = fmaxf(__fsub_rn(rx, lx), 0.0f);
                    float ih = fmaxf(__fsub_rn(ry, ly), 0.0f);
                    float inter = __fmul_rn(iw, ih);
                    float areaB = __fmul_rn(__fsub_rn(mx2, mx1), __fsub_rn(my2, my1));
                    float denom = __fadd_rn(__fsub_rn(__fadd_rn(areaA, areaB), inter), 1e-9f);
                    bool s = (m != lane) && (inter > __fmul_rn(IOU_T, denom));
                    if (m < 32) sb_lo |= ((u32)s) << m;
                    else        sb_hi |= ((u32)s) << (m - 32);
                }

                u64 eligible = validmask & ~supprev;
                u64 mysb = (((u64)sb_hi << 32) | (u64)sb_lo);
                bool iselig = (eligible >> lane) & 1ull;
                u64 edgeball = __ballot(iselig && ((mysb & eligible & below) != 0ull));

                u64 keptm;
                int cap = MAXDET - nk;
                if (edgeball == 0ull) {
                    int rank = __popcll(eligible & below);
                    keptm = __ballot(iselig && (rank < cap));
                } else {
                    u64 km = 0ull;
                    int cnt = 0;
                    for (int m = 0; m < 64 && cnt < cap; ++m) {
                        if (!((validmask >> m) & 1ull)) break;
                        if ((supprev >> m) & 1ull) continue;
                        u32 mlo = (u32)__shfl((int)sb_lo, m);
                        u32 mhi = (u32)__shfl((int)sb_hi, m);
                        u64 supby = (((u64)mhi << 32) | (u64)mlo);
                        if (supby & km) continue;
                        km |= 1ull << m;
                        ++cnt;
                    }
                    keptm = km;
                }

                if ((keptm >> lane) & 1ull) {
                    int pos = nk + __popcll(keptm & below);
                    L.fin.v.nms.kb[pos] = make_float4(x1, y1, x2, y2);
                    float* row = ob + pos * 6;
                    row[0] = bx1; row[1] = by1; row[2] = bx2; row[3] = by2;
                    row[4] = sc;  row[5] = cl;
                }
                __threadfence_block();
                nk += __popcll(keptm);
                if (nk >= MAXDET) break;
                if (validmask != ~0ull) break;
            }
        }

        for (int x = nk * 6 + lane; x < MAXDET * 6; x += 64) ob[x] = 0.0f;
    }
}

extern "C" void kernel_launch(void* const* d_in, const int* in_sizes, int n_in,
                              void* d_out, int out_size, void* d_ws, size_t ws_size,
                              hipStream_t stream) {
    const float* preds = (const float*)d_in[0];
    float* out = (float*)d_out;

    // keys first for 16B alignment of uint4 accesses
    u64* keys     = (u64*)d_ws;                            // 1.6 MB
    u64* cand_g   = keys + (size_t)BATCH * NPRED;          // 256 KB
    u32* bstart_g = (u32*)(cand_g + (size_t)BATCH * CANDMAX);   // 128 KB
    u32* balloc_g = bstart_g + BATCH * NBUCKET;            // 128 KB (sacrificial)
    int* tb_g     = (int*)(balloc_g + BATCH * NBUCKET);
    u32* stored_g = (u32*)(tb_g + 8);
    unsigned char* cls8 = (unsigned char*)(stored_g + 8);  // 200 KB

    void* args[] = {
        (void*)&preds, (void*)&keys, (void*)&cls8,
        (void*)&bstart_g, (void*)&balloc_g, (void*)&tb_g,
        (void*)&stored_g, (void*)&cand_g, (void*)&out
    };
    hipLaunchCooperativeKernel((const void*)k_mega, dim3(GRID), dim3(BLK),
                               args, 0, stream);
}

// Round 14
// 55.929 us; speedup vs baseline: 2.8681x; 2.8681x over previous
//
#include <hip/hip_runtime.h>

#define BATCH 8
#define NPRED 25200
#define NCLS 80
#define ROWW 85
#define TOPKK 2048
#define MAXDET 300
#define CANDMAX 4096
#define NBUCKET 4096
#define CONF_T 0.2f
#define IOU_T 0.6f
#define CLS_OFF 4096.0f

#define MASKN 384              // candidates with precomputed masks
#define MCH (MASKN / 64)       // 6 chunks
#define MW 13                  // u32 stride per mask row (gcd(13,32)=1: conflict-free)

typedef unsigned long long u64;
typedef unsigned int u32;

__device__ __forceinline__ int bucket_of_key(u64 k) {
    float sc = __uint_as_float((u32)(k >> 32));
    int bkt = (int)(sc * (float)NBUCKET);
    return (bkt > NBUCKET - 1) ? (NBUCKET - 1) : bkt;
}

// ---------------- K1: score/key via async global->LDS staging ----------------
__global__ __launch_bounds__(256) void k_score(
    const float* __restrict__ preds,
    u64* __restrict__ keys,
    unsigned char* __restrict__ cls8)
{
    __shared__ float4 rows4[64 * ROWW / 4 + 4];   // 1360 float4 + pad
    const int t = threadIdx.x;
    const int lane = t & 63;
    const int wave = t >> 6;
    const size_t rowbase = (size_t)blockIdx.x * 64;
    const float4* src = reinterpret_cast<const float4*>(preds + rowbase * ROWW);

    // 21 full wave-chunks of 64 float4s each (1344), tail 16 via regular store
    for (int q = wave; q < 21; q += 4) {
        __builtin_amdgcn_global_load_lds(
            (const __attribute__((address_space(1))) void*)(src + q * 64 + lane),
            (__attribute__((address_space(3))) void*)(rows4 + q * 64),
            16, 0, 0);
    }
    if (t < 16) rows4[1344 + t] = src[1344 + t];
    __syncthreads();

    const float* rows = reinterpret_cast<const float*>(rows4);
    const int r = t >> 2;          // row within tile (0..63)
    const int j = t & 3;           // quad lane
    const float* p = rows + r * ROWW;
    const float obj = p[4];

    // classes j, j+4, ..., j+76 (20 per quad lane); strict > keeps lowest index
    float best = -1.0f;
    int bi = 0;
    #pragma unroll
    for (int tt = 0; tt < 20; ++tt) {
        int c = j + 4 * tt;
        float s = __fmul_rn(obj, p[5 + c]);
        if (s > best) { best = s; bi = c; }
    }
    // quad merge: higher score wins; tie -> lower class index (global first-argmax)
    #pragma unroll
    for (int d = 1; d <= 2; d <<= 1) {
        float os = __shfl_xor(best, d);
        int oi = __shfl_xor(bi, d);
        if (os > best || (os == best && oi < bi)) { best = os; bi = oi; }
    }

    if (j == 0) {
        unsigned gid = (unsigned)rowbase + r;
        u64 key = 0ull;
        if (best > CONF_T) {
            key = ((u64)__float_as_uint(best) << 32) | (0xFFFFFFFFu - (gid % NPRED));
        }
        keys[gid] = key;
        cls8[gid] = (unsigned char)bi;
    }
}

// -------- K2: per-batch LDS hist (vectorized key pass) + suffix scan + threshold ----
// No pre-zeroed global state anywhere: hist lives in LDS, tables are written fresh.
__global__ __launch_bounds__(1024) void k_scan(
    const u64* __restrict__ keys,
    u32* __restrict__ bstart_g,
    u32* __restrict__ balloc_g,
    int* __restrict__ tb_g,
    u32* __restrict__ stored_g)
{
    __shared__ u32 histL[NBUCKET];   // 16 KB
    __shared__ u32 wtot[16];
    __shared__ u32 wsuf[16];
    __shared__ int s_tb;
    __shared__ u32 s_stored;

    const int b = blockIdx.x;
    const int t = threadIdx.x;
    const int lane = t & 63;
    const int wave = t >> 6;

    for (int i = t; i < NBUCKET; i += 1024) histL[i] = 0u;
    __syncthreads();

    // vectorized key pass: 2 keys per uint4, 12.3 rounds of coalesced loads
    const uint4* k4 = reinterpret_cast<const uint4*>(keys + (size_t)b * NPRED);
    for (int i = t; i < NPRED / 2; i += 1024) {
        uint4 v = k4[i];
        u64 ka = ((u64)v.y << 32) | v.x;
        u64 kb = ((u64)v.w << 32) | v.z;
        if (ka) atomicAdd(&histL[bucket_of_key(ka)], 1u);
        if (kb) atomicAdd(&histL[bucket_of_key(kb)], 1u);
    }
    __syncthreads();

    u32 h0 = histL[4 * t], h1 = histL[4 * t + 1], h2 = histL[4 * t + 2], h3 = histL[4 * t + 3];
    u32 ps = h0 + h1 + h2 + h3;

    // in-wave inclusive suffix (Kogge-Stone via shfl_down)
    u32 v = ps;
    #pragma unroll
    for (int off = 1; off < 64; off <<= 1) {
        u32 u2 = __shfl_down(v, off);
        if (lane + off < 64) v += u2;
    }
    if (lane == 0) wtot[wave] = v;
    __syncthreads();
    if (t < 16) {
        u32 w = wtot[t];
        u32 s = w;
        #pragma unroll
        for (int off = 1; off < 16; off <<= 1) {
            u32 u2 = __shfl_down(s, off);
            if (t + off < 16) s += u2;
        }
        wsuf[t] = s - w;
    }
    if (t == 0) s_tb = 0;
    __syncthreads();
    u32 suffix_t = v + wsuf[wave];        // sum of ps[t..1023]
    u32 snext = suffix_t - ps;            // buckets > 4t+3

    u32 b3 = snext;
    u32 b2 = b3 + h3;
    u32 b1 = b2 + h2;
    u32 b0 = b1 + h1;
    const size_t B0 = (size_t)b * NBUCKET;
    bstart_g[B0 + 4 * t + 0] = b0;
    bstart_g[B0 + 4 * t + 1] = b1;
    bstart_g[B0 + 4 * t + 2] = b2;
    bstart_g[B0 + 4 * t + 3] = b3;
    balloc_g[B0 + 4 * t + 0] = b0;       // sacrificial alloc counters for k_compact
    balloc_g[B0 + 4 * t + 1] = b1;
    balloc_g[B0 + 4 * t + 2] = b2;
    balloc_g[B0 + 4 * t + 3] = b3;

    if (t == 0) s_stored = (suffix_t < (u32)CANDMAX) ? suffix_t : (u32)CANDMAX;
    __syncthreads();
    {
        u32 c3 = b3 + h3, c2 = b2 + h2, c1 = b1 + h1, c0 = b0 + h0;
        if (c3 >= TOPKK && b3 < TOPKK) { s_tb = 4 * t + 3; s_stored = (c3 < (u32)CANDMAX) ? c3 : (u32)CANDMAX; }
        if (c2 >= TOPKK && b2 < TOPKK) { s_tb = 4 * t + 2; s_stored = (c2 < (u32)CANDMAX) ? c2 : (u32)CANDMAX; }
        if (c1 >= TOPKK && b1 < TOPKK) { s_tb = 4 * t + 1; s_stored = (c1 < (u32)CANDMAX) ? c1 : (u32)CANDMAX; }
        if (c0 >= TOPKK && b0 < TOPKK) { s_tb = 4 * t + 0; s_stored = (c0 < (u32)CANDMAX) ? c0 : (u32)CANDMAX; }
    }
    __syncthreads();
    if (t == 0) { tb_g[b] = s_tb; stored_g[b] = s_stored; }
}

// ---------------- K3: chip-wide vectorized compaction (allocates via balloc_g) ------
__global__ __launch_bounds__(256) void k_compact(
    const u64* __restrict__ keys,
    u32* __restrict__ balloc_g,
    const int* __restrict__ tb_g,
    u64* __restrict__ cand_g)
{
    unsigned i2 = blockIdx.x * 256 + threadIdx.x;        // pair index
    if (i2 >= BATCH * NPRED / 2) return;
    uint4 v = reinterpret_cast<const uint4*>(keys)[i2];
    int b = (int)(i2 / (NPRED / 2));
    int tb = tb_g[b];
    u64 ka = ((u64)v.y << 32) | v.x;
    u64 kb = ((u64)v.w << 32) | v.z;
    if (ka) {
        int bkt = bucket_of_key(ka);
        if (bkt >= tb) {
            u32 slot = atomicAdd(&balloc_g[(size_t)b * NBUCKET + bkt], 1u);
            if (slot < CANDMAX) cand_g[(size_t)b * CANDMAX + slot] = ka;
        }
    }
    if (kb) {
        int bkt = bucket_of_key(kb);
        if (bkt >= tb) {
            u32 slot = atomicAdd(&balloc_g[(size_t)b * NBUCKET + bkt], 1u);
            if (slot < CANDMAX) cand_g[(size_t)b * CANDMAX + slot] = kb;
        }
    }
}

// ---------------- K4: rank + mask-matrix NMS over ~stored candidates ----------------
// bucket end derived from bstart[bkt-1] (= bstart[bkt]+hist[bkt]) — no hist needed.
struct RankPhase {
    u32 bstartL[NBUCKET];                // 16 KB (only [tb-1..) filled/used)
};
struct NmsPhase {
    u32 masks32[MASKN * MW];             // 19968 B (upper-triangle masks)
    float4 cbx[MASKN];                   // offset boxes
    float carea[MASKN];
    float4 kb[MAXDET];                   // kept offset boxes
};

__global__ __launch_bounds__(1024) void k_finish(
    const float* __restrict__ preds,
    const unsigned char* __restrict__ cls8,
    const u32* __restrict__ bstart_g,
    const int* __restrict__ tb_g,
    const u32* __restrict__ stored_g,
    const u64* __restrict__ cand_g,
    float* __restrict__ out)
{
    __shared__ union { RankPhase rk; NmsPhase nms; } u;   // 32 KB
    __shared__ u64 candL[CANDMAX];                        // 32 KB
    __shared__ unsigned short rank2cand[TOPKK];           // 4 KB
    __shared__ float4 sbox[MASKN];                        // 6 KB (original boxes)
    __shared__ float sscore[MASKN];
    __shared__ float scls[MASKN];
    __shared__ u64 validw[MCH];

    const int b = blockIdx.x;
    const int t = threadIdx.x;
    const int lane = t & 63;
    const int wave = t >> 6;
    float* ob = out + (size_t)b * MAXDET * 6;
    const u32 stored = stored_g[b];
    const int tb = tb_g[b];
    const int tb2 = (tb > 0) ? tb - 1 : 0;

    // load live bstart slice [tb-1..NBUCKET)
    for (int i = tb2 + t; i < NBUCKET; i += 1024)
        u.rk.bstartL[i] = bstart_g[(size_t)b * NBUCKET + i];
    for (int i = t; i < TOPKK; i += 1024) rank2cand[i] = 0xFFFFu;
    for (int i = t; i < CANDMAX; i += 1024)
        if ((u32)i < stored) candL[i] = cand_g[(size_t)b * CANDMAX + i];
    if (t < MASKN) {
        sbox[t] = make_float4(0.f, 0.f, 0.f, 0.f);
        sscore[t] = 0.f;
        scls[t] = 0.f;
    }
    __syncthreads();

    // exact rank (bucket-local comparison count) + fill top-384 boxes
    for (u32 i = t; i < stored; i += 1024) {
        u64 k = candL[i];
        int bkt = bucket_of_key(k);
        u32 base = u.rk.bstartL[bkt];
        u32 end = (bkt == 0) ? stored : u.rk.bstartL[bkt - 1];
        if (end > stored) end = stored;
        u32 r = base;
        for (u32 jx = base; jx < end; ++jx) r += (candL[jx] > k) ? 1u : 0u;
        if (r < TOPKK) rank2cand[r] = (unsigned short)i;
        if (r < MASKN) {
            float sc = __uint_as_float((u32)(k >> 32));
            unsigned idx = 0xFFFFFFFFu - (u32)(k & 0xFFFFFFFFu);
            const float* p = preds + ((size_t)b * NPRED + idx) * ROWW;
            float cx = p[0], cy = p[1], w = p[2], h = p[3];
            float hw = __fmul_rn(w, 0.5f);
            float hh = __fmul_rn(h, 0.5f);
            sbox[r] = make_float4(__fsub_rn(cx, hw), __fsub_rn(cy, hh),
                                  __fadd_rn(cx, hw), __fadd_rn(cy, hh));
            sscore[r] = sc;
            scls[r] = (float)cls8[(size_t)b * NPRED + idx];
        }
    }
    __syncthreads();   // rank LDS dead; union switches to NMS phase

    // phase 1: offset boxes, areas, valid bits
    if (t < MASKN) {
        float sc = sscore[t];
        float cl = scls[t];
        float4 bb = sbox[t];
        float off = __fmul_rn(cl, CLS_OFF);
        float4 obx = make_float4(__fadd_rn(bb.x, off), __fadd_rn(bb.y, off),
                                 __fadd_rn(bb.z, off), __fadd_rn(bb.w, off));
        u.nms.cbx[t] = obx;
        u.nms.carea[t] = __fmul_rn(__fsub_rn(obx.z, obx.x), __fsub_rn(obx.w, obx.y));
        u64 vb = __ballot(sc > CONF_T);
        if (lane == 0) validw[wave] = vb;
    }
    __syncthreads();

    // phase 2: upper-triangle masks, 42 units over 16 waves
    for (int tu = 0; tu < 3; ++tu) {
        int uidx = wave + 16 * tu;
        if (uidx >= 42) break;
        int q, s;
        if (uidx < 12)      { q = 0; s = uidx; }
        else if (uidx < 22) { q = 1; s = uidx - 12 + 2; }
        else if (uidx < 30) { q = 2; s = uidx - 22 + 4; }
        else if (uidx < 36) { q = 3; s = uidx - 30 + 6; }
        else if (uidx < 40) { q = 4; s = uidx - 36 + 8; }
        else                { q = 5; s = uidx - 40 + 10; }

        const int r = q * 64 + lane;
        const float4 me = u.nms.cbx[r];
        const float aA = u.nms.carea[r];
        const int j0 = s * 32;
        u32 acc = 0u;
        #pragma unroll 8
        for (int jj = 0; jj < 32; ++jj) {
            const int jx = j0 + jj;
            float4 cb = u.nms.cbx[jx];
            float lx = fmaxf(me.x, cb.x), ly = fmaxf(me.y, cb.y);
            float rx = fminf(me.z, cb.z), ry = fminf(me.w, cb.w);
            float iw = fmaxf(__fsub_rn(rx, lx), 0.0f);
            float ih = fmaxf(__fsub_rn(ry, ly), 0.0f);
            float inter = __fmul_rn(iw, ih);
            float denom = __fadd_rn(__fsub_rn(__fadd_rn(aA, u.nms.carea[jx]), inter), 1e-9f);
            bool sv = inter > __fmul_rn(IOU_T, denom);
            acc |= ((u32)sv) << jj;
        }
        if (s == 2 * q || s == 2 * q + 1) {     // diagonal slice: keep only j > r
            int shift = r - j0;
            u32 dm = (shift < 0) ? ~0u : ((shift >= 31) ? 0u : (~0u << (shift + 1)));
            acc &= dm;
        }
        u.nms.masks32[r * MW + s] = acc;
    }
    __syncthreads();
    if (wave != 0) return;

    // phase 3: wave-0 greedy resolve (upper-triangle semantics)
    const u64 below = (lane == 0) ? 0ull : (~0ull >> (64 - lane));
    u64 S[MCH];
    #pragma unroll
    for (int w = 0; w < MCH; ++w) S[w] = 0ull;
    int nk = 0;
    bool done = false, allfull = true;

    #pragma unroll
    for (int c = 0; c < MCH; ++c) {
        if (done) break;
        u64 vw = validw[c];
        u64 eligible = vw & ~S[c];
        const int rbase = (c * 64 + lane) * MW;
        u64 Mu = ((u64)u.nms.masks32[rbase + 2 * c + 1] << 32) |
                 (u64)u.nms.masks32[rbase + 2 * c];
        bool elig = (eligible >> lane) & 1ull;
        if (eligible) {
            int cap = MAXDET - nk;
            u64 edge = __ballot(elig && ((Mu & eligible) != 0ull));
            u64 keptm;
            if (edge == 0ull) {
                int rank = __popcll(eligible & below);
                keptm = __ballot(elig && (rank < cap));
            } else {
                u64 km = 0ull, supm = 0ull;
                int cnt = 0;
                for (int m = 0; m < 64 && cnt < cap; ++m) {
                    if (!((eligible >> m) & 1ull)) continue;
                    if ((supm >> m) & 1ull) continue;
                    km |= 1ull << m;
                    ++cnt;
                    supm |= __shfl(Mu, m);
                }
                keptm = km;
            }
            if ((keptm >> lane) & 1ull) {
                int pos = nk + __popcll(keptm & below);
                int i = c * 64 + lane;
                float4 bb = sbox[i];
                u.nms.kb[pos] = u.nms.cbx[i];
                float* row = ob + pos * 6;
                row[0] = bb.x; row[1] = bb.y; row[2] = bb.z; row[3] = bb.w;
                row[4] = sscore[i]; row[5] = scls[i];
            }
            nk += __popcll(keptm);
            if (nk >= MAXDET) {
                done = true;
            } else if (keptm) {
                for (int w = c + 1; w < MCH; ++w) {
                    u64 v2 = ((keptm >> lane) & 1ull)
                        ? (((u64)u.nms.masks32[rbase + 2 * w + 1] << 32) |
                           (u64)u.nms.masks32[rbase + 2 * w])
                        : 0ull;
                    v2 |= __shfl_xor(v2, 1);  v2 |= __shfl_xor(v2, 2);
                    v2 |= __shfl_xor(v2, 4);  v2 |= __shfl_xor(v2, 8);
                    v2 |= __shfl_xor(v2, 16); v2 |= __shfl_xor(v2, 32);
                    S[w] |= v2;
                }
            }
        }
        if (vw != ~0ull) { allfull = false; break; }
    }

    // phase 4: exact fallback beyond MASKN (rarely taken) — gathers from preds on demand
    if (!done && allfull && nk < MAXDET) {
        __threadfence_block();
        for (int c = MCH; c < TOPKK / 64; ++c) {
            int r = c * 64 + lane;
            unsigned short ci = rank2cand[r];
            bool valid = (ci != 0xFFFFu);
            u64 validmask = __ballot(valid);
            if (validmask == 0ull) break;

            float sc = 0.f, cl = 0.f;
            float bx1 = 0.f, by1 = 0.f, bx2 = 0.f, by2 = 0.f;
            if (valid) {
                u64 k = candL[ci];
                sc = __uint_as_float((u32)(k >> 32));
                unsigned idx = 0xFFFFFFFFu - (u32)(k & 0xFFFFFFFFu);
                const float* p = preds + ((size_t)b * NPRED + idx) * ROWW;
                float cx = p[0], cy = p[1], w = p[2], h = p[3];
                float hw = __fmul_rn(w, 0.5f);
                float hh = __fmul_rn(h, 0.5f);
                bx1 = __fsub_rn(cx, hw); by1 = __fsub_rn(cy, hh);
                bx2 = __fadd_rn(cx, hw); by2 = __fadd_rn(cy, hh);
                cl = (float)cls8[(size_t)b * NPRED + idx];
            }
            float off = __fmul_rn(cl, CLS_OFF);
            float x1 = __fadd_rn(bx1, off), y1 = __fadd_rn(by1, off);
            float x2 = __fadd_rn(bx2, off), y2 = __fadd_rn(by2, off);
            float areaA = __fmul_rn(__fsub_rn(x2, x1), __fsub_rn(y2, y1));

            bool sup = false;
            for (int jx = 0; jx < nk; ++jx) {
                float4 k4 = u.nms.kb[jx];
                float lx = fmaxf(x1, k4.x), ly = fmaxf(y1, k4.y);
                float rx = fminf(x2, k4.z), ry = fminf(y2, k4.w);
                float iw = fmaxf(__fsub_rn(rx, lx), 0.0f);
                float ih = fmaxf(__fsub_rn(ry, ly), 0.0f);
                float inter = __fmul_rn(iw, ih);
                float areaB = __fmul_rn(__fsub_rn(k4.z, k4.x), __fsub_rn(k4.w, k4.y));
                float denom = __fadd_rn(__fsub_rn(__fadd_rn(areaA, areaB), inter), 1e-9f);
                if (inter > __fmul_rn(IOU_T, denom)) sup = true;
            }
            u64 supprev = __ballot(sup);

            u32 sb_lo = 0u, sb_hi = 0u;
            for (int m = 0; m < 64; ++m) {
                float mx1 = __shfl(x1, m), my1 = __shfl(y1, m);
                float mx2 = __shfl(x2, m), my2 = __shfl(y2, m);
                float lx = fmaxf(x1, mx1), ly = fmaxf(y1, my1);
                float rx = fminf(x2, mx2), ry = fminf(y2, my2);
                float iw = fmaxf(__fsub_rn(rx, lx), 0.0f);
                float ih = fmaxf(__fsub_rn(ry, ly), 0.0f);
                float inter = __fmul_rn(iw, ih);
                float areaB = __fmul_rn(__fsub_rn(mx2, mx1), __fsub_rn(my2, my1));
                float denom = __fadd_rn(__fsub_rn(__fadd_rn(areaA, areaB), inter), 1e-9f);
                bool s = (m != lane) && (inter > __fmul_rn(IOU_T, denom));
                if (m < 32) sb_lo |= ((u32)s) << m;
                else        sb_hi |= ((u32)s) << (m - 32);
            }

            u64 eligible = validmask & ~supprev;
            u64 mysb = (((u64)sb_hi << 32) | (u64)sb_lo);
            bool iselig = (eligible >> lane) & 1ull;
            u64 edgeball = __ballot(iselig && ((mysb & eligible & below) != 0ull));

            u64 keptm;
            int cap = MAXDET - nk;
            if (edgeball == 0ull) {
                int rank = __popcll(eligible & below);
                keptm = __ballot(iselig && (rank < cap));
            } else {
                u64 km = 0ull;
                int cnt = 0;
                for (int m = 0; m < 64 && cnt < cap; ++m) {
                    if (!((validmask >> m) & 1ull)) break;
                    if ((supprev >> m) & 1ull) continue;
                    u32 mlo = (u32)__shfl((int)sb_lo, m);
                    u32 mhi = (u32)__shfl((int)sb_hi, m);
                    u64 supby = (((u64)mhi << 32) | (u64)mlo);
                    if (supby & km) continue;
                    km |= 1ull << m;
                    ++cnt;
                }
                keptm = km;
            }

            if ((keptm >> lane) & 1ull) {
                int pos = nk + __popcll(keptm & below);
                u.nms.kb[pos] = make_float4(x1, y1, x2, y2);
                float* row = ob + pos * 6;
                row[0] = bx1; row[1] = by1; row[2] = bx2; row[3] = by2;
                row[4] = sc;  row[5] = cl;
            }
            __threadfence_block();
            nk += __popcll(keptm);
            if (nk >= MAXDET) break;
            if (validmask != ~0ull) break;
        }
    }

    for (int x = nk * 6 + lane; x < MAXDET * 6; x += 64) ob[x] = 0.0f;
}

extern "C" void kernel_launch(void* const* d_in, const int* in_sizes, int n_in,
                              void* d_out, int out_size, void* d_ws, size_t ws_size,
                              hipStream_t stream) {
    const float* preds = (const float*)d_in[0];
    float* out = (float*)d_out;

    // keys first for 16B alignment of uint4 accesses
    u64* keys     = (u64*)d_ws;                            // 1.6 MB
    u64* cand_g   = keys + (size_t)BATCH * NPRED;          // 256 KB
    u32* bstart_g = (u32*)(cand_g + (size_t)BATCH * CANDMAX);   // 128 KB
    u32* balloc_g = bstart_g + BATCH * NBUCKET;            // 128 KB (sacrificial)
    int* tb_g     = (int*)(balloc_g + BATCH * NBUCKET);
    u32* stored_g = (u32*)(tb_g + 8);
    unsigned char* cls8 = (unsigned char*)(stored_g + 8);  // 200 KB

    hipLaunchKernelGGL(k_score, dim3(BATCH * NPRED / 64), dim3(256), 0, stream,
                       preds, keys, cls8);
    hipLaunchKernelGGL(k_scan, dim3(BATCH), dim3(1024), 0, stream,
                       keys, bstart_g, balloc_g, tb_g, stored_g);
    hipLaunchKernelGGL(k_compact, dim3((BATCH * NPRED / 2 + 255) / 256), dim3(256), 0, stream,
                       keys, balloc_g, tb_g, cand_g);
    hipLaunchKernelGGL(k_finish, dim3(BATCH), dim3(1024), 0, stream,
                       preds, cls8, bstart_g, tb_g, stored_g, cand_g, out);
}